// Round 5
// baseline (338.871 us; speedup 1.0000x reference)
//
#include <hip/hip_runtime.h>

// Full output LUT in d_ws: for each 12-bit pattern P, the complete 32-float
// output row [s0: pb0..2,v0..4 | s1 | s2 | s3]. Size: 4096*32 floats = 512 KB.

typedef int   vint4   __attribute__((ext_vector_type(4)));
typedef float vfloat4 __attribute__((ext_vector_type(4)));

__global__ __launch_bounds__(256) void build_lut_kernel(
    const float* __restrict__ pat,   // (4,3,4096)
    const float* __restrict__ pos,   // (4,5,4096)
    const int*   __restrict__ conn,  // (4,5,12)
    float* __restrict__ lut)         // (4096,32)
{
    int t = blockIdx.x * 256 + threadIdx.x;   // 0..16383
    if (t >= 4096 * 4) return;
    int P = t >> 2;          // pattern, 12 bits
    int s = t & 3;           // scale
    int n = s + 1;
    int tn = 3 * n;          // ctx bits
    int in_bits = tn + 3;    // ctx + pbits
    int nb = in_bits < 12 ? in_bits : 12;
    unsigned mask = (1u << tn) - 1u;
    unsigned a = (unsigned)P & mask;          // paddr for this scale

    // pos_in bit j (j<tn) is paddr bit (tn-1-j)
    unsigned posmask = 0;
    for (int j = 0; j < tn; ++j)
        posmask |= ((a >> (tn - 1 - j)) & 1u) << j;

    float outv[8];
    for (int j = 0; j < 3; ++j) {
        float v = pat[(s * 3 + j) * 4096 + (int)a];
        unsigned b = (v > 0.5f) ? 1u : 0u;
        outv[j] = (float)b;
        posmask |= b << (tn + j);
    }
    for (int k = 0; k < 5; ++k) {
        unsigned addr = 0;
        for (int j = 0; j < nb; ++j) {
            int c = conn[(s * 5 + k) * 12 + j] % in_bits;
            addr |= ((posmask >> c) & 1u) << j;
        }
        outv[3 + k] = pos[(s * 5 + k) * 4096 + (int)addr];
    }
    float4* d4 = (float4*)(lut + (size_t)P * 32 + s * 8);
    d4[0] = make_float4(outv[0], outv[1], outv[2], outv[3]);
    d4[1] = make_float4(outv[4], outv[5], outv[6], outv[7]);
}

__global__ __launch_bounds__(256) void gather_kernel(
    const vint4* __restrict__ tb4,       // type_bits as int4: 3 per sample
    const float4* __restrict__ lut4,     // 4096 * 8 float4 (L2-resident)
    float4* __restrict__ out4,           // nsamp*8 float4
    int nsamp)
{
    // 512 samples per block. pnib[part*512 + sampleLocal] = pre-shifted nibble.
    __shared__ unsigned pnib[1536];      // 6 KB
    int t = threadIdx.x;
    bool full = ((long long)(blockIdx.x + 1) * 512) <= (long long)nsamp;

    // --- Stage + pack: 6 exactly-once fully-sequential nt loads per thread
    // (24 KB contiguous per block), nibble written pre-shifted, conflict-free.
    long long base  = (long long)blockIdx.x * 1536;  // int4 index
    long long limit = (long long)nsamp * 3;
#pragma unroll
    for (int r = 0; r < 6; ++r) {
        int l = r * 256 + t;                         // 0..1535
        vint4 v = {0, 0, 0, 0};
        if (full || base + l < limit) v = __builtin_nontemporal_load(tb4 + base + l);
        int sl = l / 3, part = l - sl * 3;
        unsigned nib = ((unsigned)v.x << 3) | ((unsigned)v.y << 2)
                     | ((unsigned)v.z << 1) |  (unsigned)v.w;
        pnib[part * 512 + sl] = nib << (8 - 4 * part);
    }
    __syncthreads();

    // --- Thread t owns within-sample chunk c = t&7; 8 lanes per sample read
    // lut4[Ps*8 + 0..7]: one contiguous 128B L2-resident row per sample.
    int c    = t & 7;
    int srow = t >> 3;
    const float4* lutc = lut4 + c;
    long long outBase = (long long)blockIdx.x * 4096 + t;

    if (full) {
        // Two pipelined 8-deep batches: batch h+1's loads issue while batch h
        // stores drain; all 8 loads of a batch are in flight together.
#pragma unroll
        for (int h = 0; h < 2; ++h) {
            unsigned Ps[8];
#pragma unroll
            for (int i = 0; i < 8; ++i) {
                int sl = (h * 8 + i) * 32 + srow;
                Ps[i] = pnib[sl] | pnib[512 + sl] | pnib[1024 + sl];
            }
            float4 vbuf[8];
#pragma unroll
            for (int i = 0; i < 8; ++i)
                vbuf[i] = lutc[(size_t)Ps[i] * 8];
#pragma unroll
            for (int i = 0; i < 8; ++i)
                __builtin_nontemporal_store(*(const vfloat4*)&vbuf[i],
                    (vfloat4*)&out4[outBase + (long long)((h * 8 + i) * 256)]);
        }
    } else {
        long long total4 = (long long)nsamp * 8;
#pragma unroll
        for (int i = 0; i < 16; ++i) {
            int sl = i * 32 + srow;
            unsigned Ps = pnib[sl] | pnib[512 + sl] | pnib[1024 + sl];
            long long g = outBase + (long long)(i * 256);
            if (g < total4) {
                float4 v = lutc[(size_t)Ps * 8];
                __builtin_nontemporal_store(*(const vfloat4*)&v, (vfloat4*)&out4[g]);
            }
        }
    }
}

extern "C" void kernel_launch(void* const* d_in, const int* in_sizes, int n_in,
                              void* d_out, int out_size, void* d_ws, size_t ws_size,
                              hipStream_t stream) {
    const int*   type_bits = (const int*)d_in[0];
    const float* pat       = (const float*)d_in[1];
    const float* pos       = (const float*)d_in[2];
    const int*   conn      = (const int*)d_in[3];
    float* lut = (float*)d_ws;   // needs 524,288 B

    int nsamp = in_sizes[0] / 12;                    // 2,000,000

    build_lut_kernel<<<(4096 * 4 + 255) / 256, 256, 0, stream>>>(pat, pos, conn, lut);
    int nblocks = (nsamp + 511) / 512;               // 512 samples per block
    gather_kernel<<<nblocks, 256, 0, stream>>>((const vint4*)type_bits,
                                               (const float4*)lut,
                                               (float4*)d_out, nsamp);
}

// Round 6
// 329.830 us; speedup vs baseline: 1.0274x; 1.0274x over previous
//
#include <hip/hip_runtime.h>

// Full output LUT in d_ws: for each 12-bit pattern P, the complete 32-float
// output row [s0: pb0..2,v0..4 | s1 | s2 | s3]. Size: 4096*32 floats = 512 KB.

typedef int   vint4   __attribute__((ext_vector_type(4)));
typedef float vfloat4 __attribute__((ext_vector_type(4)));

__global__ __launch_bounds__(256) void build_lut_kernel(
    const float* __restrict__ pat,   // (4,3,4096)
    const float* __restrict__ pos,   // (4,5,4096)
    const int*   __restrict__ conn,  // (4,5,12)
    float* __restrict__ lut)         // (4096,32)
{
    int t = blockIdx.x * 256 + threadIdx.x;   // 0..16383
    if (t >= 4096 * 4) return;
    int P = t >> 2;          // pattern, 12 bits
    int s = t & 3;           // scale
    int n = s + 1;
    int tn = 3 * n;          // ctx bits
    int in_bits = tn + 3;    // ctx + pbits
    int nb = in_bits < 12 ? in_bits : 12;
    unsigned mask = (1u << tn) - 1u;
    unsigned a = (unsigned)P & mask;          // paddr for this scale

    // pos_in bit j (j<tn) is paddr bit (tn-1-j)
    unsigned posmask = 0;
    for (int j = 0; j < tn; ++j)
        posmask |= ((a >> (tn - 1 - j)) & 1u) << j;

    float outv[8];
    for (int j = 0; j < 3; ++j) {
        float v = pat[(s * 3 + j) * 4096 + (int)a];
        unsigned b = (v > 0.5f) ? 1u : 0u;
        outv[j] = (float)b;
        posmask |= b << (tn + j);
    }
    for (int k = 0; k < 5; ++k) {
        unsigned addr = 0;
        for (int j = 0; j < nb; ++j) {
            int c = conn[(s * 5 + k) * 12 + j] % in_bits;
            addr |= ((posmask >> c) & 1u) << j;
        }
        outv[3 + k] = pos[(s * 5 + k) * 4096 + (int)addr];
    }
    float4* d4 = (float4*)(lut + (size_t)P * 32 + s * 8);
    d4[0] = make_float4(outv[0], outv[1], outv[2], outv[3]);
    d4[1] = make_float4(outv[4], outv[5], outv[6], outv[7]);
}

__global__ __launch_bounds__(256) void gather_kernel(
    const vint4* __restrict__ tb4,       // type_bits as int4: 3 per sample
    const float4* __restrict__ lut4,     // 4096 * 8 float4 (L2-resident)
    float4* __restrict__ out4,           // nsamp*8 float4
    int nsamp)
{
    // pnib[part*256 + sampleLocal] holds the pre-shifted 4-bit nibble of P:
    // part 0 -> bits 11..8, part 1 -> bits 7..4, part 2 -> bits 3..0.
    __shared__ unsigned pnib[768];       // 3 KB
    int t = threadIdx.x;
    bool full = ((long long)(blockIdx.x + 1) * 256) <= (long long)nsamp;

    // --- Stage + pack: exactly-once fully-sequential nt loads (lane i reads
    // byte 16*i of a contiguous 4 KB span), nibble written pre-shifted.
    long long base  = (long long)blockIdx.x * 768;   // int4 index
    long long limit = (long long)nsamp * 3;
#pragma unroll
    for (int r = 0; r < 3; ++r) {
        int l = r * 256 + t;                         // 0..767
        vint4 v = {0, 0, 0, 0};
        if (full || base + l < limit) v = __builtin_nontemporal_load(tb4 + base + l);
        int sl = l / 3, part = l - sl * 3;
        unsigned nib = ((unsigned)v.x << 3) | ((unsigned)v.y << 2)
                     | ((unsigned)v.z << 1) |  (unsigned)v.w;
        pnib[part * 256 + sl] = nib << (8 - 4 * part);
    }
    __syncthreads();

    // --- Thread t owns within-sample chunk c = t&7 (one float4 of the 128B row).
    // The 8 lanes sharing a sample read lut4[Ps*8 + 0..7]: 128B contiguous L2 hit.
    int c    = t & 7;
    int srow = t >> 3;
    const float4* lutc = lut4 + c;
    long long outBase = (long long)blockIdx.x * 2048 + t;

    unsigned Ps[8];
#pragma unroll
    for (int i = 0; i < 8; ++i) {
        int sl = i * 32 + srow;
        // 3 stride-4B LDS reads, broadcast within each 8-lane group: conflict-free
        Ps[i] = pnib[sl] | pnib[256 + sl] | pnib[512 + sl];
    }
    float4 vbuf[8];
#pragma unroll
    for (int i = 0; i < 8; ++i)
        vbuf[i] = lutc[(size_t)Ps[i] * 8];           // all 8 loads in flight

    if (full) {
#pragma unroll
        for (int i = 0; i < 8; ++i)
            __builtin_nontemporal_store(*(const vfloat4*)&vbuf[i],
                                        (vfloat4*)&out4[outBase + (long long)(i * 256)]);
    } else {
        long long total4 = (long long)nsamp * 8;
#pragma unroll
        for (int i = 0; i < 8; ++i) {
            long long g = outBase + (long long)(i * 256);
            if (g < total4)
                __builtin_nontemporal_store(*(const vfloat4*)&vbuf[i],
                                            (vfloat4*)&out4[g]);
        }
    }
}

extern "C" void kernel_launch(void* const* d_in, const int* in_sizes, int n_in,
                              void* d_out, int out_size, void* d_ws, size_t ws_size,
                              hipStream_t stream) {
    const int*   type_bits = (const int*)d_in[0];
    const float* pat       = (const float*)d_in[1];
    const float* pos       = (const float*)d_in[2];
    const int*   conn      = (const int*)d_in[3];
    float* lut = (float*)d_ws;   // needs 524,288 B

    int nsamp = in_sizes[0] / 12;                    // 2,000,000

    build_lut_kernel<<<(4096 * 4 + 255) / 256, 256, 0, stream>>>(pat, pos, conn, lut);
    int nblocks = (nsamp + 255) / 256;
    gather_kernel<<<nblocks, 256, 0, stream>>>((const vint4*)type_bits,
                                               (const float4*)lut,
                                               (float4*)d_out, nsamp);
}